// Round 1
// baseline (3312.551 us; speedup 1.0000x reference)
//
#include <hip/hip_runtime.h>
#include <cstdint>
#include <cstddef>

// Problem constants (fixed by the reference).
constexpr int kN  = 25000;
constexpr int kE  = 400000;
constexpr int kEN = kE + kN;   // edges + self loops
constexpr int kD  = 64;
constexpr int kH  = 4;
constexpr int kHD = 256;       // H * DH

__device__ __forceinline__ float lrelu02(float x){ return x > 0.f ? x : 0.2f*x; }

// ---------------- CSR build ----------------
__global__ void k_deg(const int* __restrict__ col, int* __restrict__ deg){
  int i = blockIdx.x*256 + threadIdx.x;
  if (i < kE) atomicAdd(&deg[col[i]], 1);
}

__global__ void k_scan(const int* __restrict__ deg, int* __restrict__ col_start){
  __shared__ int lds[1024];
  __shared__ int carry_s;
  int t = threadIdx.x;
  if (t == 0) carry_s = 0;
  __syncthreads();
  for (int base = 0; base < kN; base += 1024){
    int v = (base + t < kN) ? deg[base + t] : 0;
    lds[t] = v; __syncthreads();
    for (int off = 1; off < 1024; off <<= 1){
      int add = (t >= off) ? lds[t - off] : 0;
      __syncthreads();
      lds[t] += add;
      __syncthreads();
    }
    int incl = lds[t];
    int carry = carry_s;
    if (base + t < kN) col_start[base + t] = carry + incl - v;
    __syncthreads();
    if (t == 0) carry_s = carry + lds[1023];
    __syncthreads();
  }
  if (t == 0) col_start[kN] = carry_s;
}

__global__ void k_fill(const int* __restrict__ col, const int* __restrict__ col_start,
                       int* __restrict__ fill, int* __restrict__ edge_ids){
  int i = blockIdx.x*256 + threadIdx.x;
  if (i < kE){
    int c = col[i];
    int p = atomicAdd(&fill[c], 1);
    edge_ids[col_start[c] + p] = i;
  }
}

// ---------------- initial embeddings ----------------
__global__ void k_x0(const float* __restrict__ nf, const float* __restrict__ W,
                     const float* __restrict__ b, float* __restrict__ x){
  int i = blockIdx.x*256 + threadIdx.x;
  if (i >= kN*kD) return;
  int n = i >> 6, d = i & 63;
  float acc = b[d];
#pragma unroll
  for (int k = 0; k < 16; k++) acc += nf[n*16 + k] * W[k*64 + d];
  x[i] = fmaxf(acc, 0.f);
}

__global__ void k_e0(const float* __restrict__ ea, const float* __restrict__ W,
                     const float* __restrict__ b, float* __restrict__ e){
  long long i = (long long)blockIdx.x*256 + threadIdx.x;
  if (i >= (long long)kE*kD) return;
  int n = (int)(i >> 6), d = (int)(i & 63);
  float acc = b[d];
#pragma unroll
  for (int k = 0; k < 4; k++) acc += ea[n*4 + k] * W[k*64 + d];
  e[i] = fmaxf(acc, 0.f);
}

// ---------------- per-layer: xl = x@Wl+bl, xr = x@Wr+br  (N x 256 each) ----------------
#define XLR_NPB 8
__global__ __launch_bounds__(256) void k_xlr(const float* __restrict__ x,
    const float* __restrict__ Wl, const float* __restrict__ bl,
    const float* __restrict__ Wr, const float* __restrict__ br,
    float* __restrict__ xl, float* __restrict__ xr){
  __shared__ float xs[XLR_NPB*64];
  int j = threadIdx.x;
  int n0 = blockIdx.x * XLR_NPB;
  for (int i = j; i < XLR_NPB*64; i += 256){
    int n = n0 + (i >> 6);
    xs[i] = (n < kN) ? x[(size_t)n*64 + (i & 63)] : 0.f;
  }
  __syncthreads();
  float accl[XLR_NPB], accr[XLR_NPB];
  float blv = bl[j], brv = br[j];
#pragma unroll
  for (int t = 0; t < XLR_NPB; t++){ accl[t] = blv; accr[t] = brv; }
  for (int k = 0; k < 64; k++){
    float wl = Wl[k*kHD + j], wr = Wr[k*kHD + j];
#pragma unroll
    for (int t = 0; t < XLR_NPB; t++){
      float xv = xs[t*64 + k];
      accl[t] += xv * wl; accr[t] += xv * wr;
    }
  }
#pragma unroll
  for (int t = 0; t < XLR_NPB; t++){
    int n = n0 + t;
    if (n < kN){ xl[(size_t)n*kHD + j] = accl[t]; xr[(size_t)n*kHD + j] = accr[t]; }
  }
}

// ---------------- per-layer: e_loop[n] = mean of incoming e rows ----------------
__global__ __launch_bounds__(256) void k_eloop(const float* __restrict__ e,
    const int* __restrict__ col_start, const int* __restrict__ edge_ids,
    float* __restrict__ e_loop){
  int wave = threadIdx.x >> 6, lane = threadIdx.x & 63;
  int n = blockIdx.x*4 + wave;
  if (n >= kN) return;
  int s0 = col_start[n], s1 = col_start[n+1];
  float acc = 0.f;
  for (int p = s0; p < s1; p++){
    int eid = edge_ids[p];
    acc += e[(size_t)eid*64 + lane];
  }
  int dg = s1 - s0;
  e_loop[(size_t)n*64 + lane] = acc / (float)(dg > 0 ? dg : 1);
}

// ---------------- per-layer: scores for all EN "edges" (real + self-loop) ----------------
// thread j owns We column j in registers; block processes edges grid-strided.
__global__ __launch_bounds__(256) void k_score(
    const float* __restrict__ e, const float* __restrict__ e_loop,
    const float* __restrict__ xl, const float* __restrict__ xr,
    const int* __restrict__ row, const int* __restrict__ col,
    const float* __restrict__ We, const float* __restrict__ att,
    float* __restrict__ score){
  int j = threadIdx.x;
  float w[64];
#pragma unroll
  for (int k = 0; k < 64; k++) w[k] = We[k*kHD + j];
  float attv = att[j];
  __shared__ float elds[64];
  int h = j >> 6;   // wave id == head
  for (int eid = blockIdx.x; eid < kEN; eid += gridDim.x){
    int r, c; const float* erow;
    if (eid < kE){ r = row[eid]; c = col[eid]; erow = e + (size_t)eid*64; }
    else         { r = c = eid - kE;           erow = e_loop + (size_t)r*64; }
    __syncthreads();
    if (j < 16) ((float4*)elds)[j] = ((const float4*)erow)[j];
    __syncthreads();
    float xls = xl[(size_t)r*kHD + j];
    float xrs = xr[(size_t)c*kHD + j];
    float a0=0.f, a1=0.f, a2=0.f, a3=0.f;
    const float4* ep = (const float4*)elds;
#pragma unroll
    for (int k4 = 0; k4 < 16; k4++){
      float4 v = ep[k4];
      a0 += v.x * w[k4*4+0]; a1 += v.y * w[k4*4+1];
      a2 += v.z * w[k4*4+2]; a3 += v.w * w[k4*4+3];
    }
    float msg = ((a0+a1)+(a2+a3)) + xls + xrs;
    float vv = lrelu02(msg) * attv;
#pragma unroll
    for (int off = 32; off; off >>= 1) vv += __shfl_xor(vv, off);
    if ((j & 63) == 0) score[(size_t)eid*kH + h] = vv;
  }
}

// ---------------- per-layer: segment max & expsum (incl self-loop) ----------------
__global__ void k_segmax(const float* __restrict__ score,
    const int* __restrict__ col_start, const int* __restrict__ edge_ids,
    float* __restrict__ mmax, float* __restrict__ ssum){
  int i = blockIdx.x*256 + threadIdx.x;
  if (i >= kN*kH) return;
  int n = i >> 2, h = i & 3;
  float selfsc = score[(size_t)(kE + n)*kH + h];
  float m = selfsc;
  int s0 = col_start[n], s1 = col_start[n+1];
  for (int p = s0; p < s1; p++)
    m = fmaxf(m, score[(size_t)edge_ids[p]*kH + h]);
  float s = expf(selfsc - m);
  for (int p = s0; p < s1; p++)
    s += expf(score[(size_t)edge_ids[p]*kH + h] - m);
  mmax[i] = m; ssum[i] = s;
}

// ---------------- per-layer: aggregate + head-mean + residual + LN + relu ----------------
__global__ __launch_bounds__(256) void k_agg_ln(
    const float* __restrict__ xl, const float* __restrict__ score,
    const int* __restrict__ row,
    const int* __restrict__ col_start, const int* __restrict__ edge_ids,
    const float* __restrict__ mmax, const float* __restrict__ ssum,
    const float* __restrict__ conv_b, const float* __restrict__ ln_g,
    const float* __restrict__ ln_b, float* __restrict__ x){
  int n = blockIdx.x;
  int j = threadIdx.x, h = j >> 6, d = j & 63;
  float m = mmax[n*4 + h];
  float inv = 1.f / ssum[n*4 + h];
  // self loop
  float a = expf(score[(size_t)(kE + n)*kH + h] - m) * inv;
  float acc = a * xl[(size_t)n*kHD + j];
  int s0 = col_start[n], s1 = col_start[n+1];
  for (int p = s0; p < s1; p++){
    int eid = edge_ids[p];
    int r = row[eid];
    float ae = expf(score[(size_t)eid*kH + h] - m) * inv;
    acc += ae * xl[(size_t)r*kHD + j];
  }
  __shared__ float lds[256];
  lds[j] = acc; __syncthreads();
  if (j < 64){
    float upd = (lds[d] + lds[64+d] + lds[128+d] + lds[192+d]) * 0.25f + conv_b[d];
    float y = x[(size_t)n*64 + d] + upd;
    float mu = y;
#pragma unroll
    for (int off = 32; off; off >>= 1) mu += __shfl_xor(mu, off);
    mu *= (1.f/64.f);
    float diff = y - mu;
    float var = diff * diff;
#pragma unroll
    for (int off = 32; off; off >>= 1) var += __shfl_xor(var, off);
    var *= (1.f/64.f);
    float out = diff * rsqrtf(var + 1e-5f) * ln_g[d] + ln_b[d];
    x[(size_t)n*64 + d] = fmaxf(out, 0.f);
  }
}

// ---------------- per-layer: P = x@W1a + b1, Q = x@W1b  (node-level split of edge MLP) --
#define PQ_NPB 16
__global__ __launch_bounds__(256) void k_pq(const float* __restrict__ x,
    const float* __restrict__ W1, const float* __restrict__ b1,
    float* __restrict__ P, float* __restrict__ Q){
  __shared__ float xs[PQ_NPB*64];
  int tid = threadIdx.x;
  int j = tid & 63;
  int s = tid >> 6;     // 0..3, each handles 4 nodes
  int n0 = blockIdx.x * PQ_NPB;
  for (int i = tid; i < PQ_NPB*64; i += 256){
    int n = n0 + (i >> 6);
    xs[i] = (n < kN) ? x[(size_t)n*64 + (i & 63)] : 0.f;
  }
  __syncthreads();
  float accP[4], accQ[4];
  float b1v = b1[j];
#pragma unroll
  for (int t = 0; t < 4; t++){ accP[t] = b1v; accQ[t] = 0.f; }
  for (int k = 0; k < 64; k++){
    float wa = W1[k*64 + j];          // rows 0..63  : x[row] part
    float wb = W1[(64 + k)*64 + j];   // rows 64..127: x[col] part
#pragma unroll
    for (int t = 0; t < 4; t++){
      float xv = xs[(s*4 + t)*64 + k];
      accP[t] += xv * wa; accQ[t] += xv * wb;
    }
  }
#pragma unroll
  for (int t = 0; t < 4; t++){
    int n = n0 + s*4 + t;
    if (n < kN){ P[(size_t)n*64 + j] = accP[t]; Q[(size_t)n*64 + j] = accQ[t]; }
  }
}

// ---------------- per-layer: edge MLP  e = relu(e + (relu(P[r]+Q[c]+e@W1c)@W2 + b2)) ----
__global__ __launch_bounds__(256) void k_mlp(
    const float* __restrict__ P, const float* __restrict__ Q,
    const float* __restrict__ W1c, const float* __restrict__ W2,
    const float* __restrict__ b2,
    const int* __restrict__ row, const int* __restrict__ col,
    float* __restrict__ e){
  __shared__ float ec_lds[4][64];
  __shared__ float h_lds[4][64];
  float w1[64], w2[64];
  int lane = threadIdx.x & 63, wave = threadIdx.x >> 6;
#pragma unroll
  for (int k = 0; k < 64; k++){ w1[k] = W1c[k*64 + lane]; w2[k] = W2[k*64 + lane]; }
  float b2v = b2[lane];
  int widx = blockIdx.x*4 + wave, nw = gridDim.x*4;
  for (int eid = widx; eid < kE; eid += nw){
    int r = row[eid], c = col[eid];
    float ec = e[(size_t)eid*64 + lane];
    float hp = P[(size_t)r*64 + lane] + Q[(size_t)c*64 + lane];
    ec_lds[wave][lane] = ec;
    float h0=0.f,h1=0.f,h2=0.f,h3=0.f;
    const float4* ep = (const float4*)&ec_lds[wave][0];
#pragma unroll
    for (int k4 = 0; k4 < 16; k4++){
      float4 v = ep[k4];
      h0 += v.x * w1[k4*4+0]; h1 += v.y * w1[k4*4+1];
      h2 += v.z * w1[k4*4+2]; h3 += v.w * w1[k4*4+3];
    }
    float h = fmaxf(hp + ((h0+h1)+(h2+h3)), 0.f);
    h_lds[wave][lane] = h;
    float o0=b2v,o1=0.f,o2=0.f,o3=0.f;
    const float4* hq = (const float4*)&h_lds[wave][0];
#pragma unroll
    for (int k4 = 0; k4 < 16; k4++){
      float4 v = hq[k4];
      o0 += v.x * w2[k4*4+0]; o1 += v.y * w2[k4*4+1];
      o2 += v.z * w2[k4*4+2]; o3 += v.w * w2[k4*4+3];
    }
    e[(size_t)eid*64 + lane] = fmaxf(ec + ((o0+o1)+(o2+o3)), 0.f);
  }
}

// ---------------- host ----------------
extern "C" void kernel_launch(void* const* d_in, const int* in_sizes, int n_in,
                              void* d_out, int out_size, void* d_ws, size_t ws_size,
                              hipStream_t stream) {
  const float* node_feat = (const float*)d_in[0];
  const int*   edge_idx  = (const int*)d_in[1];
  const float* edge_attr = (const float*)d_in[2];
  const float* W_node = (const float*)d_in[3];
  const float* b_node = (const float*)d_in[4];
  const float* W_edge = (const float*)d_in[5];
  const float* b_edge = (const float*)d_in[6];
  const float* Wl   = (const float*)d_in[7];
  const float* bl   = (const float*)d_in[8];
  const float* Wr   = (const float*)d_in[9];
  const float* br   = (const float*)d_in[10];
  const float* We   = (const float*)d_in[11];
  const float* att  = (const float*)d_in[12];
  const float* cvb  = (const float*)d_in[13];
  const float* lng  = (const float*)d_in[14];
  const float* lnb  = (const float*)d_in[15];
  const float* euW1 = (const float*)d_in[16];
  const float* eub1 = (const float*)d_in[17];
  const float* euW2 = (const float*)d_in[18];
  const float* eub2 = (const float*)d_in[19];

  const int* row = edge_idx;
  const int* col = edge_idx + kE;

  float* x = (float*)d_out;                      // N x 64
  float* e = (float*)d_out + (size_t)kN*kD;      // E x 64

  // carve workspace
  char* p = (char*)d_ws;
  auto carve = [&](size_t bytes)->void*{
    void* r = (void*)p;
    p += (bytes + 255) & ~(size_t)255;
    return r;
  };
  float* xl     = (float*)carve((size_t)kN*kHD*4);
  float* xr     = (float*)carve((size_t)kN*kHD*4);
  float* P      = (float*)carve((size_t)kN*kD*4);
  float* Q      = (float*)carve((size_t)kN*kD*4);
  float* e_loop = (float*)carve((size_t)kN*kD*4);
  float* score  = (float*)carve((size_t)kEN*kH*4);
  float* mmax   = (float*)carve((size_t)kN*kH*4);
  float* ssum   = (float*)carve((size_t)kN*kH*4);
  int* deg      = (int*)carve((size_t)kN*4);
  int* col_start= (int*)carve((size_t)(kN+1)*4);
  int* fill     = (int*)carve((size_t)kN*4);
  int* edge_ids = (int*)carve((size_t)kE*4);

  // CSR build (graph is layer-invariant)
  hipMemsetAsync(deg, 0, (size_t)kN*4, stream);
  hipMemsetAsync(fill, 0, (size_t)kN*4, stream);
  k_deg<<<(kE+255)/256, 256, 0, stream>>>(col, deg);
  k_scan<<<1, 1024, 0, stream>>>(deg, col_start);
  k_fill<<<(kE+255)/256, 256, 0, stream>>>(col, col_start, fill, edge_ids);

  // initial embeddings
  k_x0<<<(kN*kD+255)/256, 256, 0, stream>>>(node_feat, W_node, b_node, x);
  k_e0<<<(kE*kD+255)/256, 256, 0, stream>>>(edge_attr, W_edge, b_edge, e);

  for (int i = 0; i < 3; i++){
    const float* Wl_i  = Wl  + (size_t)i*kD*kHD;
    const float* bl_i  = bl  + (size_t)i*kHD;
    const float* Wr_i  = Wr  + (size_t)i*kD*kHD;
    const float* br_i  = br  + (size_t)i*kHD;
    const float* We_i  = We  + (size_t)i*kD*kHD;
    const float* att_i = att + (size_t)i*kHD;
    const float* cvb_i = cvb + (size_t)i*kD;
    const float* lng_i = lng + (size_t)i*kD;
    const float* lnb_i = lnb + (size_t)i*kD;
    const float* W1_i  = euW1 + (size_t)i*192*64;
    const float* b1_i  = eub1 + (size_t)i*kD;
    const float* W2_i  = euW2 + (size_t)i*64*64;
    const float* b2_i  = eub2 + (size_t)i*kD;

    k_xlr<<<(kN + XLR_NPB - 1)/XLR_NPB, 256, 0, stream>>>(x, Wl_i, bl_i, Wr_i, br_i, xl, xr);
    k_eloop<<<(kN + 3)/4, 256, 0, stream>>>(e, col_start, edge_ids, e_loop);
    k_score<<<2048, 256, 0, stream>>>(e, e_loop, xl, xr, row, col, We_i, att_i, score);
    k_segmax<<<(kN*kH + 255)/256, 256, 0, stream>>>(score, col_start, edge_ids, mmax, ssum);
    k_agg_ln<<<kN, 256, 0, stream>>>(xl, score, row, col_start, edge_ids, mmax, ssum,
                                     cvb_i, lng_i, lnb_i, x);
    k_pq<<<(kN + PQ_NPB - 1)/PQ_NPB, 256, 0, stream>>>(x, W1_i, b1_i, P, Q);
    k_mlp<<<2048, 256, 0, stream>>>(P, Q, W1_i + 128*64, W2_i, b2_i, row, col, e);
  }
}